// Round 3
// baseline (1161.474 us; speedup 1.0000x reference)
//
#include <hip/hip_runtime.h>
#include <math.h>

#define NB 16
#define DKC 512
#define NP 2048

typedef __attribute__((ext_vector_type(4))) float f32x4;

// ---------------------------------------------------------------------------
// Round-3 BISECTION kernel.
// Scores computed with plain fp32 VALU FMAs (no MFMA, no bf16 split, no LDS
// swizzle). Downstream fused: per-block softmax-weighted correspondences ->
// 15 per-batch moments accumulated via f64 global atomics (only 1.9 KB of
// d_ws used, zeroed with hipMemsetAsync each launch).
//   PASS  => bug was in the MFMA / split-bf16 / swizzle cluster (round 2).
//   FAIL  => bug is in softmax fusion concept / Kabsch / output plumbing.
//
// Block = (batch, 128-row n-tile): 16x16 = 256 blocks, 512 threads (8 waves).
// Thread (ty 0..15, tx 0..31) owns rows n0+ty*8..+7, cols m0+tx+32j (j<16).
// m-loop: 4 tiles of 512 columns. k-loop: 32 slices of 16.
// ---------------------------------------------------------------------------
__global__ __launch_bounds__(512, 1) void attn_moments_valu(
    const float* __restrict__ src_emb,
    const float* __restrict__ tgt_emb,
    const float* __restrict__ src_pts,
    const float* __restrict__ tgt_pts,
    const float* __restrict__ temperature,
    double* __restrict__ moments)
{
    __shared__ float Qf[16 * 128];   // [k][n]  8 KB
    __shared__ float Kf[16 * 512];   // [k][m] 32 KB

    const int b  = blockIdx.x >> 4;
    const int nt = blockIdx.x & 15;
    const int n0 = nt * 128;
    const int tid = threadIdx.x;
    const int ty = tid >> 5;          // 0..15
    const int tx = tid & 31;          // 0..31

    // exp(temp * S_raw / sqrt(512)) = exp2(c2 * S_raw)
    const float c2 = temperature[b] * (0.044194173824159216f * 1.4426950408889634f);
    const size_t ebase = (size_t)b * DKC * NP;
    const size_t pb3   = (size_t)b * 3 * NP;

    float den[8], nx[8], ny[8], nz[8];
#pragma unroll
    for (int r = 0; r < 8; ++r) { den[r] = 0.f; nx[r] = 0.f; ny[r] = 0.f; nz[r] = 0.f; }

    for (int mt = 0; mt < 4; ++mt) {
        const int m0 = mt * 512;
        float acc[8][16];
#pragma unroll
        for (int r = 0; r < 8; ++r)
#pragma unroll
            for (int j = 0; j < 16; ++j) acc[r][j] = 0.f;

        for (int kc = 0; kc < 32; ++kc) {
            const int kb = kc * 16;
            __syncthreads();   // previous compute done reading LDS
            {   // stage Q slice: 16k x 128n, one float4 per thread
                const int k = tid >> 5, n4 = (tid & 31) * 4;
                *(f32x4*)&Qf[k * 128 + n4] =
                    *(const f32x4*)(src_emb + ebase + (size_t)(kb + k) * NP + n0 + n4);
            }
#pragma unroll
            for (int e = 0; e < 4; ++e) {   // stage K slice: 16k x 512m
                const int lin = tid + e * 512;
                const int k = lin >> 7, m4 = (lin & 127) * 4;
                *(f32x4*)&Kf[k * 512 + m4] =
                    *(const f32x4*)(tgt_emb + ebase + (size_t)(kb + k) * NP + m0 + m4);
            }
            __syncthreads();

#pragma unroll
            for (int k = 0; k < 16; ++k) {
                const f32x4 a0 = *(const f32x4*)&Qf[k * 128 + ty * 8];
                const f32x4 a1 = *(const f32x4*)&Qf[k * 128 + ty * 8 + 4];
                float bv[16];
#pragma unroll
                for (int j = 0; j < 16; ++j) bv[j] = Kf[k * 512 + tx + 32 * j];
#pragma unroll
                for (int r = 0; r < 8; ++r) {
                    const float av = (r < 4) ? a0[r] : a1[r - 4];
#pragma unroll
                    for (int j = 0; j < 16; ++j)
                        acc[r][j] = fmaf(av, bv[j], acc[r][j]);
                }
            }
        }

        // epilogue: p = exp2(c2*s); accumulate denominator + weighted tgt sums
#pragma unroll
        for (int j = 0; j < 16; ++j) {
            const int mc = m0 + tx + 32 * j;
            const float t0 = tgt_pts[pb3 + mc];
            const float t1 = tgt_pts[pb3 + NP + mc];
            const float t2 = tgt_pts[pb3 + 2 * NP + mc];
#pragma unroll
            for (int r = 0; r < 8; ++r) {
                const float p = exp2f(c2 * acc[r][j]);
                den[r] += p;
                nx[r] += p * t0;
                ny[r] += p * t1;
                nz[r] += p * t2;
            }
        }
    }

    // reduce the 32 tx lanes of each ty-group (offsets stay within 32-half)
#pragma unroll
    for (int r = 0; r < 8; ++r) {
#pragma unroll
        for (int off = 1; off <= 16; off <<= 1) {
            den[r] += __shfl_xor(den[r], off);
            nx[r] += __shfl_xor(nx[r], off);
            ny[r] += __shfl_xor(ny[r], off);
            nz[r] += __shfl_xor(nz[r], off);
        }
    }

    if (tx == 0) {
        // rows n = n0 + ty*8 + r fully reduced; form corr and local moments
        double m15[15];
#pragma unroll
        for (int q = 0; q < 15; ++q) m15[q] = 0.0;
#pragma unroll
        for (int r = 0; r < 8; ++r) {
            const int n = n0 + ty * 8 + r;
            const double inv = 1.0 / (double)den[r];
            const double c0 = (double)nx[r] * inv;
            const double c1 = (double)ny[r] * inv;
            const double c2d = (double)nz[r] * inv;
            const double s0 = (double)src_pts[pb3 + n];
            const double s1 = (double)src_pts[pb3 + NP + n];
            const double s2 = (double)src_pts[pb3 + 2 * NP + n];
            m15[0] += s0;  m15[1] += s1;  m15[2] += s2;
            m15[3] += c0;  m15[4] += c1;  m15[5] += c2d;
            m15[6] += s0 * c0;  m15[7] += s0 * c1;  m15[8] += s0 * c2d;
            m15[9] += s1 * c0;  m15[10] += s1 * c1; m15[11] += s1 * c2d;
            m15[12] += s2 * c0; m15[13] += s2 * c1; m15[14] += s2 * c2d;
        }
        double* mb = moments + b * 15;
#pragma unroll
        for (int q = 0; q < 15; ++q) atomicAdd(&mb[q], m15[q]);
    }
}

// ---------------------------------------------------------------------------
// Finalize: per batch, Kabsch from the 15 moments (double Jacobi SVD of H^T H).
// ---------------------------------------------------------------------------
__global__ void kabsch_finalize(const double* __restrict__ moments,
                                float* __restrict__ out)
{
    const int b = blockIdx.x;
    if (threadIdx.x != 0) return;
    const double* a = moments + b * 15;

    const double invN = 1.0 / NP;
    const double mus[3] = { a[0] * invN, a[1] * invN, a[2] * invN };
    const double muc[3] = { a[3] * invN, a[4] * invN, a[5] * invN };
    double Hm[3][3];
    for (int i = 0; i < 3; ++i)
        for (int j = 0; j < 3; ++j)
            Hm[i][j] = a[6 + i * 3 + j] - (double)NP * mus[i] * muc[j];

    // Jacobi eigendecomposition of A = H^T H  ->  V, lambda = sigma^2
    double A[3][3], V[3][3] = { {1,0,0},{0,1,0},{0,0,1} };
    for (int i = 0; i < 3; ++i)
        for (int j = 0; j < 3; ++j) {
            double s = 0;
            for (int k = 0; k < 3; ++k) s += Hm[k][i] * Hm[k][j];
            A[i][j] = s;
        }
    const int PP[3] = { 0, 0, 1 }, QQ[3] = { 1, 2, 2 };
    for (int sweep = 0; sweep < 20; ++sweep) {
        for (int r = 0; r < 3; ++r) {
            const int p = PP[r], q = QQ[r];
            const double apq = A[p][q];
            if (apq * apq <= 1e-32 * A[p][p] * A[q][q]) continue;
            const double theta = (A[q][q] - A[p][p]) / (2.0 * apq);
            const double tt = (theta >= 0 ? 1.0 : -1.0) / (fabs(theta) + sqrt(1.0 + theta * theta));
            const double c = 1.0 / sqrt(1.0 + tt * tt);
            const double s = tt * c;
            for (int k = 0; k < 3; ++k) {
                const double akp = A[k][p], akq = A[k][q];
                A[k][p] = c * akp - s * akq;
                A[k][q] = s * akp + c * akq;
            }
            for (int k = 0; k < 3; ++k) {
                const double apk = A[p][k], aqk = A[q][k];
                A[p][k] = c * apk - s * aqk;
                A[q][k] = s * apk + c * aqk;
            }
            for (int k = 0; k < 3; ++k) {
                const double vkp = V[k][p], vkq = V[k][q];
                V[k][p] = c * vkp - s * vkq;
                V[k][q] = s * vkp + c * vkq;
            }
        }
    }
    int idx[3] = { 0, 1, 2 };   // sort eigenvalues descending
    for (int i = 0; i < 2; ++i)
        for (int j = i + 1; j < 3; ++j)
            if (A[idx[j]][idx[j]] > A[idx[i]][idx[i]]) { const int t = idx[i]; idx[i] = idx[j]; idx[j] = t; }
    double Vs[3][3], U[3][3];
    for (int j = 0; j < 3; ++j)
        for (int i = 0; i < 3; ++i) Vs[i][j] = V[i][idx[j]];
    for (int j = 0; j < 3; ++j) {
        double hv[3] = { 0, 0, 0 };
        for (int i = 0; i < 3; ++i)
            for (int k = 0; k < 3; ++k) hv[i] += Hm[i][k] * Vs[k][j];
        double s = sqrt(hv[0] * hv[0] + hv[1] * hv[1] + hv[2] * hv[2]);
        s = fmax(s, 1e-300);
        for (int i = 0; i < 3; ++i) U[i][j] = hv[i] / s;
    }
    double R0[3][3];
    for (int i = 0; i < 3; ++i)
        for (int j = 0; j < 3; ++j)
            R0[i][j] = Vs[i][0] * U[j][0] + Vs[i][1] * U[j][1] + Vs[i][2] * U[j][2];
    const double det =
        R0[0][0] * (R0[1][1] * R0[2][2] - R0[1][2] * R0[2][1])
      - R0[0][1] * (R0[1][0] * R0[2][2] - R0[1][2] * R0[2][0])
      + R0[0][2] * (R0[1][0] * R0[2][1] - R0[1][1] * R0[2][0]);
    const double dsg = (det < 0.0) ? -1.0 : 1.0;
    double R[3][3];
    for (int i = 0; i < 3; ++i)
        for (int j = 0; j < 3; ++j)
            R[i][j] = Vs[i][0] * U[j][0] + Vs[i][1] * U[j][1] + dsg * Vs[i][2] * U[j][2];
    for (int i = 0; i < 3; ++i)
        for (int j = 0; j < 3; ++j)
            out[b * 9 + i * 3 + j] = (float)R[i][j];
    for (int i = 0; i < 3; ++i) {
        const double ti = -(R[i][0] * mus[0] + R[i][1] * mus[1] + R[i][2] * mus[2]) + muc[i];
        out[NB * 9 + b * 3 + i] = (float)ti;
    }
}

extern "C" void kernel_launch(void* const* d_in, const int* in_sizes, int n_in,
                              void* d_out, int out_size, void* d_ws, size_t ws_size,
                              hipStream_t stream)
{
    const float* src_emb = (const float*)d_in[0];
    const float* tgt_emb = (const float*)d_in[1];
    const float* src_pts = (const float*)d_in[2];
    const float* tgt_pts = (const float*)d_in[3];
    const float* temp    = (const float*)d_in[4];
    float* out = (float*)d_out;
    double* moments = (double*)d_ws;   // 16 x 15 doubles = 1920 B

    hipMemsetAsync(d_ws, 0, NB * 15 * sizeof(double), stream);
    attn_moments_valu<<<dim3(NB * 16), dim3(512), 0, stream>>>(
        src_emb, tgt_emb, src_pts, tgt_pts, temp, moments);
    kabsch_finalize<<<dim3(NB), dim3(64), 0, stream>>>(moments, out);
}

// Round 4
// 473.549 us; speedup vs baseline: 2.4527x; 2.4527x over previous
//
#include <hip/hip_runtime.h>
#include <math.h>

#define NB 16
#define DKC 512
#define NP 2048
#define BN 128
#define BM 128
#define BK 64
#define NKC (DKC / BK)

typedef __attribute__((ext_vector_type(8))) short sh8;
typedef __attribute__((ext_vector_type(4))) float f32x4;

// ---------------------------------------------------------------------------
// Kernel 1: fused  p = exp(temp * QK^T/sqrt(dk)),  corr = (sum p*tgt)/(sum p),
// then 15 per-batch Kabsch moments via f64 atomics (round-3-validated path).
//
// Scores via split-bf16 (hi/lo truncation) x 3 MFMA => fp32-quality dots.
// Grid: 16 batches x 16 n-tiles = 256 blocks (1/CU, 104KB LDS), 512 thr = 8
// waves in a 2(n) x 4(m) grid; wave tile 64n x 32m; m-tile pairing (Q staged
// once per 2 K-tiles).
//
// ROUND-2 BUG FIX: each wave's den/num covers only its wm quarter of m.
// After the per-16-lane shuffle reduce, partials go through an 8KB LDS
// buffer and are combined ACROSS the 4 wm-waves before corr is formed
// (round 2 raced 4 partial writes to the same corr[n] -> garbage).
// ---------------------------------------------------------------------------
__global__ __launch_bounds__(512, 2) void attn_moments_mfma(
    const float* __restrict__ src_emb,
    const float* __restrict__ tgt_emb,
    const float* __restrict__ src_pts,
    const float* __restrict__ tgt_pts,
    const float* __restrict__ temperature,
    double* __restrict__ moments)
{
    __shared__ short Qhi[BN * BK];        // 16 KB
    __shared__ short Qlo[BN * BK];        // 16 KB
    __shared__ short Khi[2][BM * BK];     // 32 KB
    __shared__ short Klo[2][BM * BK];     // 32 KB
    __shared__ float cw[8][4][16][4];     // 8 KB: [wave][g][fr*4+i][quant]

    const int bid = blockIdx.x;
    const int b = bid >> 4;           // batch
    const int nt = bid & 15;          // n-tile
    const int n0 = nt * BN;

    const int tid = threadIdx.x;
    const int lane = tid & 63;
    const int wv = tid >> 6;          // wave 0..7
    const int wn = (wv >> 2) * 64;    // 0 or 64   (n sub-tile)
    const int wm = (wv & 3) * 32;     // 0..96     (m sub-tile)
    const int g = lane >> 4;          // 0..3
    const int r15 = lane & 15;

    // exp(temp * S_raw / sqrt(512)) = exp2(c2 * S_raw)
    const float c2 = temperature[b] * (0.044194173824159216f * 1.4426950408889634f);

    // softmax partials per (row-frag fr, reg i): row n = n0 + wn + fr*16 + g*4 + i
    // NOTE: covers only THIS wave's m subset until the cross-wave combine.
    float den[4][4], nx[4][4], ny[4][4], nz[4][4];
#pragma unroll
    for (int fr = 0; fr < 4; ++fr)
#pragma unroll
        for (int i = 0; i < 4; ++i) { den[fr][i] = 0.f; nx[fr][i] = 0.f; ny[fr][i] = 0.f; nz[fr][i] = 0.f; }

    // staging: thread (wv, lane) owns rows {2*lane, 2*lane+1} x k-chunk wv.
    const int kg = wv;
    const int srow = lane * 2;
    const size_t ebase = (size_t)b * DKC * NP;
    const float* gq = src_emb + ebase + n0 + srow;
    const float* gk = tgt_emb + ebase + srow;
    const size_t pb3 = (size_t)b * 3 * NP;

    // swizzle: unit = row*8 + (kg ^ (row&7) ^ ((row>>3)&7)); 16B units.
    auto stage_tile = [&](const float* gsrc, short* dhi, short* dlo, int kbase) {
        float2 v[8];
#pragma unroll
        for (int j = 0; j < 8; ++j)
            v[j] = *(const float2*)(gsrc + (size_t)(kbase + kg * 8 + j) * NP);
#pragma unroll
        for (int r = 0; r < 2; ++r) {
            const int row = srow + r;
            sh8 H, L;
#pragma unroll
            for (int j = 0; j < 8; ++j) {
                const float x = (r == 0) ? v[j].x : v[j].y;
                const unsigned u = __float_as_uint(x);
                // truncation split: hi = top 16 bits; lo = exact residual -> bf16
                const float lof = x - __uint_as_float(u & 0xffff0000u);
                H[j] = (short)(u >> 16);
                L[j] = (short)(__float_as_uint(lof) >> 16);
            }
            const int unit = row * 8 + (kg ^ (row & 7) ^ ((row >> 3) & 7));
            *(sh8*)(dhi + unit * 8) = H;
            *(sh8*)(dlo + unit * 8) = L;
        }
    };

    for (int pt = 0; pt < NP / (2 * BM); ++pt) {   // 8 m-tile pairs
        const int m0 = pt * (2 * BM);
        f32x4 acc[2][4][2];                        // [tile][fr][mf]
#pragma unroll
        for (int t = 0; t < 2; ++t)
#pragma unroll
            for (int fr = 0; fr < 4; ++fr)
#pragma unroll
                for (int mf = 0; mf < 2; ++mf) acc[t][fr][mf] = (f32x4)(0.f);

        for (int kc = 0; kc < NKC; ++kc) {
            const int kb = kc * BK;
            __syncthreads();   // previous compute done reading LDS
            stage_tile(gq,           Qhi,    Qlo,    kb);
            stage_tile(gk + m0,      Khi[0], Klo[0], kb);
            stage_tile(gk + m0 + BM, Khi[1], Klo[1], kb);
            __syncthreads();

#pragma unroll
            for (int ks = 0; ks < 2; ++ks) {
                const int slot = ks * 4 + g;
                sh8 ah[4], al[4];
#pragma unroll
                for (int fr = 0; fr < 4; ++fr) {
                    const int ar = wn + fr * 16 + r15;
                    const int unit = ar * 8 + (slot ^ (ar & 7) ^ ((ar >> 3) & 7));
                    ah[fr] = *(const sh8*)(Qhi + unit * 8);
                    al[fr] = *(const sh8*)(Qlo + unit * 8);
                }
#pragma unroll
                for (int t = 0; t < 2; ++t) {
                    sh8 bh[2], bl[2];
#pragma unroll
                    for (int mf = 0; mf < 2; ++mf) {
                        const int br = wm + mf * 16 + r15;
                        const int unit = br * 8 + (slot ^ (br & 7) ^ ((br >> 3) & 7));
                        bh[mf] = *(const sh8*)(Khi[t] + unit * 8);
                        bl[mf] = *(const sh8*)(Klo[t] + unit * 8);
                    }
#pragma unroll
                    for (int fr = 0; fr < 4; ++fr)
#pragma unroll
                        for (int mf = 0; mf < 2; ++mf) {
                            acc[t][fr][mf] = __builtin_amdgcn_mfma_f32_16x16x32_bf16(ah[fr], bh[mf], acc[t][fr][mf], 0, 0, 0);
                            acc[t][fr][mf] = __builtin_amdgcn_mfma_f32_16x16x32_bf16(ah[fr], bl[mf], acc[t][fr][mf], 0, 0, 0);
                            acc[t][fr][mf] = __builtin_amdgcn_mfma_f32_16x16x32_bf16(al[fr], bh[mf], acc[t][fr][mf], 0, 0, 0);
                        }
                }
            }
        }

        // epilogue: p = exp2(c2*s); accumulate denominator + weighted tgt sums
#pragma unroll
        for (int t = 0; t < 2; ++t)
#pragma unroll
            for (int mf = 0; mf < 2; ++mf) {
                const int mc = m0 + t * BM + wm + mf * 16 + r15;  // D col = lane&15
                const float t0 = tgt_pts[pb3 + mc];
                const float t1 = tgt_pts[pb3 + NP + mc];
                const float t2 = tgt_pts[pb3 + 2 * NP + mc];
#pragma unroll
                for (int fr = 0; fr < 4; ++fr)
#pragma unroll
                    for (int i = 0; i < 4; ++i) {
                        const float p = exp2f(c2 * acc[t][fr][mf][i]);
                        den[fr][i] += p;
                        nx[fr][i] += p * t0;
                        ny[fr][i] += p * t1;
                        nz[fr][i] += p * t2;
                    }
            }
    }

    // ---- reduction, step 1: intra-wave over the 16 lanes of each column group
#pragma unroll
    for (int fr = 0; fr < 4; ++fr)
#pragma unroll
        for (int i = 0; i < 4; ++i) {
#pragma unroll
            for (int off = 1; off <= 8; off <<= 1) {
                den[fr][i] += __shfl_xor(den[fr][i], off);
                nx[fr][i] += __shfl_xor(nx[fr][i], off);
                ny[fr][i] += __shfl_xor(ny[fr][i], off);
                nz[fr][i] += __shfl_xor(nz[fr][i], off);
            }
        }

    // ---- step 2: park wave partials in LDS (one writer per 16-lane group)
    __syncthreads();   // all waves done with tile LDS (cw is separate, but keep ordering clean)
    if (r15 == 0) {
#pragma unroll
        for (int fr = 0; fr < 4; ++fr)
#pragma unroll
            for (int i = 0; i < 4; ++i) {
                cw[wv][g][fr * 4 + i][0] = den[fr][i];
                cw[wv][g][fr * 4 + i][1] = nx[fr][i];
                cw[wv][g][fr * 4 + i][2] = ny[fr][i];
                cw[wv][g][fr * 4 + i][3] = nz[fr][i];
            }
    }
    __syncthreads();

    // ---- step 3: combine the 4 wm-waves; each of 128 threads owns one row
    if (tid < 128) {
        const int r = tid;                 // n_loc = r (positional decomposition)
        const int wnIdx = r >> 6;
        const int fi = ((r >> 4) & 3) * 4 + (r & 3);
        const int gg = (r >> 2) & 3;
        float D = 0.f, X = 0.f, Y = 0.f, Z = 0.f;
#pragma unroll
        for (int w = 0; w < 4; ++w) {
            const int wave = wnIdx * 4 + w;
            D += cw[wave][gg][fi][0];
            X += cw[wave][gg][fi][1];
            Y += cw[wave][gg][fi][2];
            Z += cw[wave][gg][fi][3];
        }
        const int n = n0 + r;
        const double inv = 1.0 / (double)D;
        const double c0 = (double)X * inv;
        const double c1 = (double)Y * inv;
        const double c2d = (double)Z * inv;
        const double s0 = (double)src_pts[pb3 + n];
        const double s1 = (double)src_pts[pb3 + NP + n];
        const double s2 = (double)src_pts[pb3 + 2 * NP + n];
        double m15[15];
        m15[0] = s0;  m15[1] = s1;  m15[2] = s2;
        m15[3] = c0;  m15[4] = c1;  m15[5] = c2d;
        m15[6] = s0 * c0;  m15[7] = s0 * c1;  m15[8] = s0 * c2d;
        m15[9] = s1 * c0;  m15[10] = s1 * c1; m15[11] = s1 * c2d;
        m15[12] = s2 * c0; m15[13] = s2 * c1; m15[14] = s2 * c2d;
        // full-wave reduce (threads 0..127 = waves 0,1 fully active)
#pragma unroll
        for (int q = 0; q < 15; ++q)
#pragma unroll
            for (int off = 1; off <= 32; off <<= 1)
                m15[q] += __shfl_xor(m15[q], off);
        if ((tid & 63) == 0) {
            double* mb = moments + b * 15;
#pragma unroll
            for (int q = 0; q < 15; ++q) atomicAdd(&mb[q], m15[q]);
        }
    }
}

// ---------------------------------------------------------------------------
// Kernel 2 (validated round 3): per batch, Kabsch from the 15 moments.
// ---------------------------------------------------------------------------
__global__ void kabsch_finalize(const double* __restrict__ moments,
                                float* __restrict__ out)
{
    const int b = blockIdx.x;
    if (threadIdx.x != 0) return;
    const double* a = moments + b * 15;

    const double invN = 1.0 / NP;
    const double mus[3] = { a[0] * invN, a[1] * invN, a[2] * invN };
    const double muc[3] = { a[3] * invN, a[4] * invN, a[5] * invN };
    double Hm[3][3];
    for (int i = 0; i < 3; ++i)
        for (int j = 0; j < 3; ++j)
            Hm[i][j] = a[6 + i * 3 + j] - (double)NP * mus[i] * muc[j];

    double A[3][3], V[3][3] = { {1,0,0},{0,1,0},{0,0,1} };
    for (int i = 0; i < 3; ++i)
        for (int j = 0; j < 3; ++j) {
            double s = 0;
            for (int k = 0; k < 3; ++k) s += Hm[k][i] * Hm[k][j];
            A[i][j] = s;
        }
    const int PP[3] = { 0, 0, 1 }, QQ[3] = { 1, 2, 2 };
    for (int sweep = 0; sweep < 20; ++sweep) {
        for (int r = 0; r < 3; ++r) {
            const int p = PP[r], q = QQ[r];
            const double apq = A[p][q];
            if (apq * apq <= 1e-32 * A[p][p] * A[q][q]) continue;
            const double theta = (A[q][q] - A[p][p]) / (2.0 * apq);
            const double tt = (theta >= 0 ? 1.0 : -1.0) / (fabs(theta) + sqrt(1.0 + theta * theta));
            const double c = 1.0 / sqrt(1.0 + tt * tt);
            const double s = tt * c;
            for (int k = 0; k < 3; ++k) {
                const double akp = A[k][p], akq = A[k][q];
                A[k][p] = c * akp - s * akq;
                A[k][q] = s * akp + c * akq;
            }
            for (int k = 0; k < 3; ++k) {
                const double apk = A[p][k], aqk = A[q][k];
                A[p][k] = c * apk - s * aqk;
                A[q][k] = s * apk + c * aqk;
            }
            for (int k = 0; k < 3; ++k) {
                const double vkp = V[k][p], vkq = V[k][q];
                V[k][p] = c * vkp - s * vkq;
                V[k][q] = s * vkp + c * vkq;
            }
        }
    }
    int idx[3] = { 0, 1, 2 };
    for (int i = 0; i < 2; ++i)
        for (int j = i + 1; j < 3; ++j)
            if (A[idx[j]][idx[j]] > A[idx[i]][idx[i]]) { const int t = idx[i]; idx[i] = idx[j]; idx[j] = t; }
    double Vs[3][3], U[3][3];
    for (int j = 0; j < 3; ++j)
        for (int i = 0; i < 3; ++i) Vs[i][j] = V[i][idx[j]];
    for (int j = 0; j < 3; ++j) {
        double hv[3] = { 0, 0, 0 };
        for (int i = 0; i < 3; ++i)
            for (int k = 0; k < 3; ++k) hv[i] += Hm[i][k] * Vs[k][j];
        double s = sqrt(hv[0] * hv[0] + hv[1] * hv[1] + hv[2] * hv[2]);
        s = fmax(s, 1e-300);
        for (int i = 0; i < 3; ++i) U[i][j] = hv[i] / s;
    }
    double R0[3][3];
    for (int i = 0; i < 3; ++i)
        for (int j = 0; j < 3; ++j)
            R0[i][j] = Vs[i][0] * U[j][0] + Vs[i][1] * U[j][1] + Vs[i][2] * U[j][2];
    const double det =
        R0[0][0] * (R0[1][1] * R0[2][2] - R0[1][2] * R0[2][1])
      - R0[0][1] * (R0[1][0] * R0[2][2] - R0[1][2] * R0[2][0])
      + R0[0][2] * (R0[1][0] * R0[2][1] - R0[1][1] * R0[2][0]);
    const double dsg = (det < 0.0) ? -1.0 : 1.0;
    double R[3][3];
    for (int i = 0; i < 3; ++i)
        for (int j = 0; j < 3; ++j)
            R[i][j] = Vs[i][0] * U[j][0] + Vs[i][1] * U[j][1] + dsg * Vs[i][2] * U[j][2];
    for (int i = 0; i < 3; ++i)
        for (int j = 0; j < 3; ++j)
            out[b * 9 + i * 3 + j] = (float)R[i][j];
    for (int i = 0; i < 3; ++i) {
        const double ti = -(R[i][0] * mus[0] + R[i][1] * mus[1] + R[i][2] * mus[2]) + muc[i];
        out[NB * 9 + b * 3 + i] = (float)ti;
    }
}

extern "C" void kernel_launch(void* const* d_in, const int* in_sizes, int n_in,
                              void* d_out, int out_size, void* d_ws, size_t ws_size,
                              hipStream_t stream)
{
    const float* src_emb = (const float*)d_in[0];
    const float* tgt_emb = (const float*)d_in[1];
    const float* src_pts = (const float*)d_in[2];
    const float* tgt_pts = (const float*)d_in[3];
    const float* temp    = (const float*)d_in[4];
    float* out = (float*)d_out;
    double* moments = (double*)d_ws;   // 16 x 15 doubles = 1920 B

    hipMemsetAsync(d_ws, 0, NB * 15 * sizeof(double), stream);
    attn_moments_mfma<<<dim3(NB * 16), dim3(512), 0, stream>>>(
        src_emb, tgt_emb, src_pts, tgt_pts, temp, moments);
    kabsch_finalize<<<dim3(NB), dim3(64), 0, stream>>>(moments, out);
}